// Round 10
// baseline (590.093 us; speedup 1.0000x reference)
//
#include <hip/hip_runtime.h>
#include <hip/hip_bf16.h>
#include <stdint.h>

#define N_ROWS 8192
#define DIM 512
#define NLAB 512
#define MARGIN_F 0.35f
#define NBLK 64                        // 8192/128 row-blocks
#define NPURE 1953                     // tiles with bi-bj >= 2
#define NDIAG 127                      // diagonal (64) + subdiagonal (63)
#define NTILE (NPURE + NDIAG)          // 2080
#define ROWSTAT_BLOCKS (N_ROWS / 4)    // 2048
#define ABREPS 6                       // ablation repeat factor (lift above fill rows)

typedef __attribute__((ext_vector_type(4))) float floatx4;
typedef __attribute__((ext_vector_type(16))) float floatx16;
typedef __attribute__((ext_vector_type(8))) int intx8;

// order-preserving float->uint map (for atomicMin/Max on floats)
__device__ __forceinline__ unsigned enc_f(float f) {
    unsigned u = __float_as_uint(f);
    return (u & 0x80000000u) ? ~u : (u | 0x80000000u);
}
__device__ __forceinline__ float dec_f(unsigned e) {
    unsigned u = (e & 0x80000000u) ? (e ^ 0x80000000u) : ~e;
    return __uint_as_float(u);
}

__device__ __forceinline__ void load_lds16(const void* g, void* l) {
    __builtin_amdgcn_global_load_lds((__attribute__((address_space(1))) void*)(void*)g,
                                     (__attribute__((address_space(3))) void*)l, 16, 0, 0);
}

// Single block: histogram of labels + exclusive scan -> offsets, zero rank counters + out.
__global__ __launch_bounds__(512) void histscan_kernel(const int* __restrict__ label,
                                                       int* __restrict__ offsetArr,
                                                       int* __restrict__ cnt,
                                                       float* __restrict__ out) {
    __shared__ int h[NLAB];
    __shared__ int sc[NLAB];
    int t = threadIdx.x;
    h[t] = 0;
    __syncthreads();
    for (int i = t; i < N_ROWS; i += 512) atomicAdd(&h[label[i]], 1);
    __syncthreads();
    int v = h[t];
    sc[t] = v;
    __syncthreads();
    for (int d = 1; d < NLAB; d <<= 1) {
        int add = (t >= d) ? sc[t - d] : 0;
        __syncthreads();
        sc[t] += add;
        __syncthreads();
    }
    offsetArr[t] = sc[t] - v;   // exclusive prefix
    cnt[t] = 0;
    if (t == 0) out[0] = 0.f;
}

// One wave per row: CE partial + fp8(e4m3) conversion scattered to label-sorted position.
// Also initializes minEnc/maxEnc.
__global__ __launch_bounds__(256) void rowstats_kernel(const float* __restrict__ x,
                                                       const int* __restrict__ label,
                                                       const int* __restrict__ offsetArr,
                                                       int* __restrict__ cnt,
                                                       unsigned char* __restrict__ a8,
                                                       int* __restrict__ sortedLabel,
                                                       float* __restrict__ cePartial,
                                                       unsigned* __restrict__ minEnc,
                                                       unsigned* __restrict__ maxEnc) {
    int gid = blockIdx.x * 256 + threadIdx.x;
    if (gid < N_ROWS) { minEnc[gid] = 0xFFFFFFFFu; maxEnc[gid] = 0u; }

    int w = threadIdx.x >> 6;
    int row = blockIdx.x * 4 + w;
    int l = threadIdx.x & 63;
    const float* xr = x + (size_t)row * DIM;
    float4 v0 = ((const float4*)xr)[2 * l];
    float4 v1 = ((const float4*)xr)[2 * l + 1];
    float vals[8] = {v0.x, v0.y, v0.z, v0.w, v1.x, v1.y, v1.z, v1.w};

    float mx = vals[0];
#pragma unroll
    for (int i = 1; i < 8; i++) mx = fmaxf(mx, vals[i]);
#pragma unroll
    for (int s = 1; s < 64; s <<= 1) mx = fmaxf(mx, __shfl_xor(mx, s, 64));

    float se = 0.f;
#pragma unroll
    for (int i = 0; i < 8; i++) se += expf(vals[i] - mx);
#pragma unroll
    for (int s = 1; s < 64; s <<= 1) se += __shfl_xor(se, s, 64);

    // sorted position for this row (counting-sort rank)
    int pos = 0;
    if (l == 0) {
        int lab = label[row];
        pos = offsetArr[lab] + atomicAdd(&cnt[lab], 1);
        sortedLabel[pos] = lab;
    }
    pos = __shfl(pos, 0, 64);

    // pack 8 fp8 e4m3 and store 8B to the sorted slot
    int w0 = __builtin_amdgcn_cvt_pk_fp8_f32(vals[0], vals[1], 0, false);
    w0 = __builtin_amdgcn_cvt_pk_fp8_f32(vals[2], vals[3], w0, true);
    int w1 = __builtin_amdgcn_cvt_pk_fp8_f32(vals[4], vals[5], 0, false);
    w1 = __builtin_amdgcn_cvt_pk_fp8_f32(vals[6], vals[7], w1, true);
    ((uint2*)(a8 + (size_t)pos * DIM))[l] = make_uint2((unsigned)w0, (unsigned)w1);

    __shared__ float wsum[4];
    if (l == 0) {
        float tl = xr[label[row]];
        wsum[w] = mx + logf(se) - tl;
    }
    __syncthreads();
    if (threadIdx.x == 0)
        cePartial[blockIdx.x] = wsum[0] + wsum[1] + wsum[2] + wsum[3];
}

// R10 DIAGNOSTIC: R4's gemm (best known, ~45us) templated into 4 dispatches so
// rocprof decomposes the stall empirically (10 schedule variants all failed the
// predicted deltas; m233-style ablation is the evidence-gathering move):
//   V0 FULL    x1: exact R4, writes real minEnc/maxEnc (correctness path).
//   V1 NOSTAGE x6: staging+vmcnt removed; ds_read+MFMA+barriers+epilogue kept
//                  (garbage values -> dummyEnc).
//   V2 STAGEONLY x6: MFMA+epilogue removed; frags kept live via XOR (rule #17).
//   V3 NOEPI   x6: full K-loop; epilogue = plain keep-alive store (no shuffles,
//                  no atomics).
// Next round: FULL-V3 = epilogue; V3-V2 = MFMA marginal; V2 = staging+barrier
// floor; V1 = loop-sans-staging. Each outcome maps to a distinct fix.
template <int V>
__global__ __launch_bounds__(256, 4) void gemm_kernel(const unsigned char* __restrict__ A,
                                                      const int* __restrict__ sortedLabel,
                                                      unsigned* __restrict__ minEnc,
                                                      unsigned* __restrict__ maxEnc,
                                                      float* __restrict__ dummyF) {
    __shared__ unsigned char As[2][128 * 64];   // 2 x 8 KB
    __shared__ unsigned char Bs[2][128 * 64];   // 2 x 8 KB
    __shared__ float redA[128][2], redB[128][2];       // Imx / Jmx
    __shared__ float redImn[128][2], redJmn[128][2];   // Imn / Jmn (diag only)
    __shared__ int labi[128], labj[128];               // labels (diag only)

    int b = blockIdx.x;
    bool diag = (b < NDIAG);
    int bi, bj;
    if (diag) {
        bi = (b < 64) ? b : (b - 63);
        bj = (b < 64) ? b : (b - 64);
    } else {
        int p = b - NDIAG;
        int ci = (int)((sqrtf(8.0f * (float)p + 1.0f) - 1.0f) * 0.5f);
        while ((ci + 1) * (ci + 2) / 2 <= p) ci++;
        while (ci * (ci + 1) / 2 > p) ci--;
        bj = p - ci * (ci + 1) / 2;
        bi = ci + 2;
    }
    int ibase = bi * 128, jbase = bj * 128;

    int t = threadIdx.x;
    int w = t >> 6, l = t & 63;
    int wm = w >> 1, wn = w & 1;
    int cl = l & 31;        // col/row lane within a 32x32 frag
    int hi = l >> 5;        // k-half select

    if (diag) {
        if (t < 128) labi[t] = sortedLabel[ibase + t];
        else labj[t - 128] = sortedLabel[jbase + t - 128];
    }

    // per-lane staging geometry (loop-invariant)
    int s0 = t, s1 = t + 256;
    int r0_ = s0 >> 2, r1_ = s1 >> 2;
    int c0_ = (s0 & 3) ^ ((r0_ >> 1) & 3);
    int c1_ = (s1 & 3) ^ ((r1_ >> 1) & 3);
    const unsigned char* srcA0 = A + (size_t)(ibase + r0_) * DIM + c0_ * 16;
    const unsigned char* srcA1 = A + (size_t)(ibase + r1_) * DIM + c1_ * 16;
    const unsigned char* srcB0 = A + (size_t)(jbase + r0_) * DIM + c0_ * 16;
    const unsigned char* srcB1 = A + (size_t)(jbase + r1_) * DIM + c1_ * 16;
    int ldo0 = s0 * 16, ldo1 = s1 * 16;

#define STAGE(KK, BUF)                                      \
    {                                                       \
        load_lds16(srcA0 + (KK) * 64, As[BUF] + ldo0);      \
        load_lds16(srcA1 + (KK) * 64, As[BUF] + ldo1);      \
        load_lds16(srcB0 + (KK) * 64, Bs[BUF] + ldo0);      \
        load_lds16(srcB1 + (KK) * 64, Bs[BUF] + ldo1);      \
    }

#define READ_FRAG(VV, TILE, RR)                                       \
    {                                                                 \
        int R_ = (RR);                                                \
        int f_ = (R_ >> 1) & 3;                                       \
        const int4* rp_ = (const int4*)((TILE) + R_ * 64);            \
        int4 lo_ = rp_[(2 * hi) ^ f_];                                \
        int4 h4_ = rp_[(2 * hi + 1) ^ f_];                            \
        VV[0] = lo_.x; VV[1] = lo_.y; VV[2] = lo_.z; VV[3] = lo_.w;   \
        VV[4] = h4_.x; VV[5] = h4_.y; VV[6] = h4_.z; VV[7] = h4_.w;   \
    }

    const int REPS = (V == 0) ? 1 : ABREPS;
    int keep = 0;   // V2 keep-alive

    for (int rep = 0; rep < REPS; rep++) {
        floatx16 acc[2][2];
#pragma unroll
        for (int a = 0; a < 2; a++)
#pragma unroll
            for (int c = 0; c < 2; c++) acc[a][c] = (floatx16)0.f;

        if constexpr (V != 1) { STAGE(0, 0); STAGE(1, 1); }
        __syncthreads();

#pragma unroll
        for (int kk = 0; kk < 8; kk++) {
            int cur = kk & 1;

            intx8 b0, b1;
            READ_FRAG(b0, Bs[cur], wn * 64 + cl);
            READ_FRAG(b1, Bs[cur], wn * 64 + 32 + cl);
#pragma unroll
            for (int tm = 0; tm < 2; tm++) {
                intx8 a;
                READ_FRAG(a, As[cur], wm * 64 + tm * 32 + cl);
                if constexpr (V == 2) {
                    // keep loads live without the matrix pipe
                    keep ^= a[0] ^ a[7] ^ b0[0] ^ b1[7];
                } else {
                    acc[tm][0] = __builtin_amdgcn_mfma_scale_f32_32x32x64_f8f6f4(
                        a, b0, acc[tm][0], 0, 0, 0, 0x7F7F7F7F, 0, 0x7F7F7F7F);
                    acc[tm][1] = __builtin_amdgcn_mfma_scale_f32_32x32x64_f8f6f4(
                        a, b1, acc[tm][1], 0, 0, 0, 0x7F7F7F7F, 0, 0x7F7F7F7F);
                }
            }

            if (kk < 7) {
                __builtin_amdgcn_s_barrier();          // all waves done reading buf[cur]
                if constexpr (V != 1) {
                    if (kk < 6) STAGE(kk + 2, cur);    // overwrite dead buffer
                    if (kk < 6) {
                        asm volatile("s_waitcnt vmcnt(4)" ::: "memory");
                    } else {
                        asm volatile("s_waitcnt vmcnt(0)" ::: "memory");
                    }
                }
                __builtin_amdgcn_sched_barrier(0);
                __builtin_amdgcn_s_barrier();          // everyone's stage(kk+1) landed
            }
        }

        // ---- epilogue ----
        const float INF = __builtin_inff();
        int rbase = 4 * hi;

        if constexpr (V == 2) {
            dummyF[(unsigned)(b * 256 + t) & 262143] = (float)keep;
        } else if constexpr (V == 3) {
            float s = 0.f;
#pragma unroll
            for (int tm = 0; tm < 2; tm++)
#pragma unroll
                for (int tn = 0; tn < 2; tn++)
#pragma unroll
                    for (int r = 0; r < 16; r++) s += acc[tm][tn][r];
            dummyF[(unsigned)(b * 256 + t) & 262143] = s;
        } else {
            // V0 / V1: the real epilogue (V1 writes garbage into dummyEnc)
            if (!diag) {
                float mxJ0 = -INF, mxJ1 = -INF;
#pragma unroll
                for (int tm = 0; tm < 2; tm++) {
                    float rm[16];
#pragma unroll
                    for (int r = 0; r < 16; r++) {
                        float v0 = acc[tm][0][r], v1 = acc[tm][1][r];
                        rm[r] = fmaxf(v0, v1);
                        mxJ0 = fmaxf(mxJ0, v0);
                        mxJ1 = fmaxf(mxJ1, v1);
                    }
#pragma unroll
                    for (int r = 0; r < 16; r++)
#pragma unroll
                        for (int s = 1; s < 32; s <<= 1)
                            rm[r] = fmaxf(rm[r], __shfl_xor(rm[r], s, 64));
                    if (cl == 0) {
#pragma unroll
                        for (int r = 0; r < 16; r++)
                            redA[wm * 64 + tm * 32 + (r & 3) + 8 * (r >> 2) + rbase][wn] = rm[r];
                    }
                }
                mxJ0 = fmaxf(mxJ0, __shfl_xor(mxJ0, 32, 64));
                mxJ1 = fmaxf(mxJ1, __shfl_xor(mxJ1, 32, 64));
                if (hi == 0) {
                    redB[wn * 64 + cl][wm] = mxJ0;
                    redB[wn * 64 + 32 + cl][wm] = mxJ1;
                }
                __syncthreads();
                if (t < 128) {
                    atomicMax(&maxEnc[ibase + t], enc_f(fmaxf(redA[t][0], redA[t][1])));
                    atomicMax(&maxEnc[jbase + t], enc_f(fmaxf(redB[t][0], redB[t][1])));
                }
                __syncthreads();   // rep isolation (redA/redB reuse)
            } else {
                int jl0 = labj[wn * 64 + cl];
                int jl1 = labj[wn * 64 + 32 + cl];
                float mnJ0 = INF, mnJ1 = INF, mxJ0 = -INF, mxJ1 = -INF;
#pragma unroll
                for (int tm = 0; tm < 2; tm++) {
                    float rmn[16], rmx[16];
#pragma unroll
                    for (int r = 0; r < 16; r++) {
                        int row_l = wm * 64 + tm * 32 + (r & 3) + 8 * (r >> 2) + rbase;
                        int il = labi[row_l];
                        float v0 = acc[tm][0][r], v1 = acc[tm][1][r];
                        bool sm0 = (jl0 == il), sm1 = (jl1 == il);
                        float a0 = sm0 ? v0 : INF, d0 = sm0 ? -INF : v0;
                        float a1 = sm1 ? v1 : INF, d1 = sm1 ? -INF : v1;
                        rmn[r] = fminf(a0, a1);
                        rmx[r] = fmaxf(d0, d1);
                        mnJ0 = fminf(mnJ0, a0); mxJ0 = fmaxf(mxJ0, d0);
                        mnJ1 = fminf(mnJ1, a1); mxJ1 = fmaxf(mxJ1, d1);
                    }
#pragma unroll
                    for (int r = 0; r < 16; r++)
#pragma unroll
                        for (int s = 1; s < 32; s <<= 1) {
                            rmn[r] = fminf(rmn[r], __shfl_xor(rmn[r], s, 64));
                            rmx[r] = fmaxf(rmx[r], __shfl_xor(rmx[r], s, 64));
                        }
                    if (cl == 0) {
#pragma unroll
                        for (int r = 0; r < 16; r++) {
                            int row_l = wm * 64 + tm * 32 + (r & 3) + 8 * (r >> 2) + rbase;
                            redImn[row_l][wn] = rmn[r];
                            redA[row_l][wn] = rmx[r];
                        }
                    }
                }
                mnJ0 = fminf(mnJ0, __shfl_xor(mnJ0, 32, 64));
                mnJ1 = fminf(mnJ1, __shfl_xor(mnJ1, 32, 64));
                mxJ0 = fmaxf(mxJ0, __shfl_xor(mxJ0, 32, 64));
                mxJ1 = fmaxf(mxJ1, __shfl_xor(mxJ1, 32, 64));
                if (hi == 0) {
                    redJmn[wn * 64 + cl][wm] = mnJ0;
                    redJmn[wn * 64 + 32 + cl][wm] = mnJ1;
                    redB[wn * 64 + cl][wm] = mxJ0;
                    redB[wn * 64 + 32 + cl][wm] = mxJ1;
                }
                __syncthreads();
                if (t < 128) {
                    atomicMin(&minEnc[ibase + t], enc_f(fminf(redImn[t][0], redImn[t][1])));
                    atomicMax(&maxEnc[ibase + t], enc_f(fmaxf(redA[t][0], redA[t][1])));
                    atomicMin(&minEnc[jbase + t], enc_f(fminf(redJmn[t][0], redJmn[t][1])));
                    atomicMax(&maxEnc[jbase + t], enc_f(fmaxf(redB[t][0], redB[t][1])));
                }
                __syncthreads();   // rep isolation
            }
        }
    }
#undef STAGE
#undef READ_FRAG
}

// 32 blocks; one float atomicAdd per block into pre-zeroed out[0].
__global__ __launch_bounds__(256) void finalize_kernel(const unsigned* __restrict__ minEnc,
                                                       const unsigned* __restrict__ maxEnc,
                                                       const float* __restrict__ cePartial,
                                                       float* __restrict__ out) {
    int gid = blockIdx.x * 256 + threadIdx.x;   // 8192 threads total
    float mn = dec_f(minEnc[gid]);
    float mxv = dec_f(maxEnc[gid]);
    // pos - neg = 2*(max_diff G - min_same G); sq_i cancels, sq_j ≈ 1 (dev ~1e-7)
    float s = fmaxf(2.0f * (mxv - mn) + MARGIN_F, 0.f);
    if (gid < ROWSTAT_BLOCKS) s += cePartial[gid];
#pragma unroll
    for (int sh = 1; sh < 64; sh <<= 1) s += __shfl_xor(s, sh, 64);
    __shared__ float red[4];
    int w = threadIdx.x >> 6, l = threadIdx.x & 63;
    if (l == 0) red[w] = s;
    __syncthreads();
    if (threadIdx.x == 0)
        atomicAdd(out, (red[0] + red[1] + red[2] + red[3]) * (1.0f / (float)N_ROWS));
}

extern "C" void kernel_launch(void* const* d_in, const int* in_sizes, int n_in,
                              void* d_out, int out_size, void* d_ws, size_t ws_size,
                              hipStream_t stream) {
    const float* x = (const float*)d_in[0];
    const int* label = (const int*)d_in[1];
    float* out = (float*)d_out;

    char* ws = (char*)d_ws;
    unsigned char* a8 = (unsigned char*)ws;                      // 4 MB fp8 sorted copy
    char* p = ws + (size_t)N_ROWS * DIM;
    unsigned* minEnc = (unsigned*)p;            p += N_ROWS * 4;
    unsigned* maxEnc = (unsigned*)p;            p += N_ROWS * 4;
    float* cePartial = (float*)p;               p += ROWSTAT_BLOCKS * 4;
    int* offsetArr = (int*)p;                   p += NLAB * 4;
    int* cnt = (int*)p;                         p += NLAB * 4;
    int* sortedLabel = (int*)p;                 p += N_ROWS * 4;
    unsigned* dummyMinE = (unsigned*)p;         p += N_ROWS * 4;
    unsigned* dummyMaxE = (unsigned*)p;         p += N_ROWS * 4;
    float* dummyF = (float*)p;                  p += 262144 * 4;   // 1 MB

    histscan_kernel<<<1, 512, 0, stream>>>(label, offsetArr, cnt, out);
    rowstats_kernel<<<ROWSTAT_BLOCKS, 256, 0, stream>>>(x, label, offsetArr, cnt, a8,
                                                        sortedLabel, cePartial, minEnc, maxEnc);
    // V0: the real computation (R4-exact)
    gemm_kernel<0><<<NTILE, 256, 0, stream>>>(a8, sortedLabel, minEnc, maxEnc, dummyF);
    // Ablations (x6 reps each; outputs diverted to dummies)
    gemm_kernel<1><<<NTILE, 256, 0, stream>>>(a8, sortedLabel, dummyMinE, dummyMaxE, dummyF);
    gemm_kernel<2><<<NTILE, 256, 0, stream>>>(a8, sortedLabel, dummyMinE, dummyMaxE, dummyF);
    gemm_kernel<3><<<NTILE, 256, 0, stream>>>(a8, sortedLabel, dummyMinE, dummyMaxE, dummyF);
    finalize_kernel<<<32, 256, 0, stream>>>(minEnc, maxEnc, cePartial, out);
}

// Round 11
// 112.487 us; speedup vs baseline: 5.2459x; 5.2459x over previous
//
#include <hip/hip_runtime.h>
#include <hip/hip_bf16.h>
#include <stdint.h>

#define N_ROWS 8192
#define DIM 512
#define NLAB 512
#define MARGIN_F 0.35f
#define NBLK 64                        // 8192/128 row-blocks
#define NPURE 1953                     // tiles with bi-bj >= 2
#define NDIAG 127                      // diagonal (64) + subdiagonal (63)
#define NTILE (NPURE + NDIAG)          // 2080 = 8 * 260
#define ROWSTAT_BLOCKS (N_ROWS / 4)    // 2048

typedef __attribute__((ext_vector_type(4))) float floatx4;
typedef __attribute__((ext_vector_type(8))) int intx8;

// order-preserving float->uint map (for atomicMin/Max on floats)
__device__ __forceinline__ unsigned enc_f(float f) {
    unsigned u = __float_as_uint(f);
    return (u & 0x80000000u) ? ~u : (u | 0x80000000u);
}
__device__ __forceinline__ float dec_f(unsigned e) {
    unsigned u = (e & 0x80000000u) ? (e ^ 0x80000000u) : ~e;
    return __uint_as_float(u);
}

__device__ __forceinline__ void load_lds16(const void* g, void* l) {
    __builtin_amdgcn_global_load_lds((__attribute__((address_space(1))) void*)(void*)g,
                                     (__attribute__((address_space(3))) void*)l, 16, 0, 0);
}

// Single block: histogram of labels + exclusive scan -> offsets, zero rank counters + out.
__global__ __launch_bounds__(512) void histscan_kernel(const int* __restrict__ label,
                                                       int* __restrict__ offsetArr,
                                                       int* __restrict__ cnt,
                                                       float* __restrict__ out) {
    __shared__ int h[NLAB];
    __shared__ int sc[NLAB];
    int t = threadIdx.x;
    h[t] = 0;
    __syncthreads();
    for (int i = t; i < N_ROWS; i += 512) atomicAdd(&h[label[i]], 1);
    __syncthreads();
    int v = h[t];
    sc[t] = v;
    __syncthreads();
    for (int d = 1; d < NLAB; d <<= 1) {
        int add = (t >= d) ? sc[t - d] : 0;
        __syncthreads();
        sc[t] += add;
        __syncthreads();
    }
    offsetArr[t] = sc[t] - v;   // exclusive prefix
    cnt[t] = 0;
    if (t == 0) out[0] = 0.f;
}

// One wave per row: CE partial + fp8(e4m3) conversion scattered to label-sorted position.
// Also initializes minEnc/maxEnc.
__global__ __launch_bounds__(256) void rowstats_kernel(const float* __restrict__ x,
                                                       const int* __restrict__ label,
                                                       const int* __restrict__ offsetArr,
                                                       int* __restrict__ cnt,
                                                       unsigned char* __restrict__ a8,
                                                       int* __restrict__ sortedLabel,
                                                       float* __restrict__ cePartial,
                                                       unsigned* __restrict__ minEnc,
                                                       unsigned* __restrict__ maxEnc) {
    int gid = blockIdx.x * 256 + threadIdx.x;
    if (gid < N_ROWS) { minEnc[gid] = 0xFFFFFFFFu; maxEnc[gid] = 0u; }

    int w = threadIdx.x >> 6;
    int row = blockIdx.x * 4 + w;
    int l = threadIdx.x & 63;
    const float* xr = x + (size_t)row * DIM;
    float4 v0 = ((const float4*)xr)[2 * l];
    float4 v1 = ((const float4*)xr)[2 * l + 1];
    float vals[8] = {v0.x, v0.y, v0.z, v0.w, v1.x, v1.y, v1.z, v1.w};

    float mx = vals[0];
#pragma unroll
    for (int i = 1; i < 8; i++) mx = fmaxf(mx, vals[i]);
#pragma unroll
    for (int s = 1; s < 64; s <<= 1) mx = fmaxf(mx, __shfl_xor(mx, s, 64));

    float se = 0.f;
#pragma unroll
    for (int i = 0; i < 8; i++) se += expf(vals[i] - mx);
#pragma unroll
    for (int s = 1; s < 64; s <<= 1) se += __shfl_xor(se, s, 64);

    // sorted position for this row (counting-sort rank)
    int pos = 0;
    if (l == 0) {
        int lab = label[row];
        pos = offsetArr[lab] + atomicAdd(&cnt[lab], 1);
        sortedLabel[pos] = lab;
    }
    pos = __shfl(pos, 0, 64);

    // pack 8 fp8 e4m3 and store 8B to the sorted slot
    int w0 = __builtin_amdgcn_cvt_pk_fp8_f32(vals[0], vals[1], 0, false);
    w0 = __builtin_amdgcn_cvt_pk_fp8_f32(vals[2], vals[3], w0, true);
    int w1 = __builtin_amdgcn_cvt_pk_fp8_f32(vals[4], vals[5], 0, false);
    w1 = __builtin_amdgcn_cvt_pk_fp8_f32(vals[6], vals[7], w1, true);
    ((uint2*)(a8 + (size_t)pos * DIM))[l] = make_uint2((unsigned)w0, (unsigned)w1);

    __shared__ float wsum[4];
    if (l == 0) {
        float tl = xr[label[row]];
        wsum[w] = mx + logf(se) - tl;
    }
    __syncthreads();
    if (threadIdx.x == 0)
        cePartial[blockIdx.x] = wsum[0] + wsum[1] + wsum[2] + wsum[3];
}

// Merged GEMM on fp8: blocks [0, NDIAG) diag/subdiag tiles (mixed epilogue),
// blocks [NDIAG, NTILE) pure tiles (max-only). 128x128 tile, BK=128,
// 16B-granule XOR-swizzled LDS, mfma_scale 16x16x128 f8f6f4 (scale=1.0),
// 2x2 waves x 4x4 frags.
// launch_bounds(256,3): ~168 unified regs/wave (R8/R5 lesson: tighter caps
// spill the unified VGPR/AGPR file; this config is the session-proven 110.3us).
//
// R11 (single variable vs the 110.3 baseline): bijective XCD swizzle.
// HW round-robins blockIdx across the 8 XCDs (b%8 -> XCD). Remap
// b = (b&7)*260 + (b>>3) so each XCD executes a CONTIGUOUS run of 260 tiles:
// consecutive pure tiles share A/B panels (working set ~2.5MB < 4MB L2/XCD)
// instead of all 8 XCDs streaming the whole 4MB operand (L2 thrash; R3/R4
// FETCH ~31MB = 7.7x operand). R5 proved the locality mechanism on this op
// (FETCH 30.9 -> 12.7MB) but its timing was confounded by a register spill;
// this is the clean A/B. R10 ablation: K-loop 33us (MFMA 7), epilogue ~12 --
// staging latency is one of the ~equal stall terms this targets.
__global__ __launch_bounds__(256, 3) void gemm_kernel(const unsigned char* __restrict__ A,
                                                      const int* __restrict__ sortedLabel,
                                                      unsigned* __restrict__ minEnc,
                                                      unsigned* __restrict__ maxEnc) {
    __shared__ unsigned char As[128 * 128];   // 16 KB
    __shared__ unsigned char Bs[128 * 128];   // 16 KB
    __shared__ float redA[128][2], redB[128][2];   // Imx / Jmx

    int b = blockIdx.x;
    b = (b & 7) * (NTILE / 8) + (b >> 3);   // R11: bijective XCD-contiguous remap
    bool diag = (b < NDIAG);
    int bi, bj;
    if (diag) {
        bi = (b < 64) ? b : (b - 63);
        bj = (b < 64) ? b : (b - 64);
    } else {
        int p = b - NDIAG;
        int ci = (int)((sqrtf(8.0f * (float)p + 1.0f) - 1.0f) * 0.5f);
        while ((ci + 1) * (ci + 2) / 2 <= p) ci++;
        while (ci * (ci + 1) / 2 > p) ci--;
        bj = p - ci * (ci + 1) / 2;
        bi = ci + 2;
    }
    int ibase = bi * 128, jbase = bj * 128;

    int t = threadIdx.x;
    int w = t >> 6, l = t & 63;
    int wm = w >> 1, wn = w & 1;
    int q = l >> 4, lm = l & 15;

    floatx4 acc[4][4];
#pragma unroll
    for (int a = 0; a < 4; a++)
#pragma unroll
        for (int c = 0; c < 4; c++) acc[a][c] = (floatx4)0.f;

    // per-lane staging geometry (loop-invariant)
    int s_r = t >> 3;                 // row within tile for this thread's slot
    int s_c = ((t & 7) ^ (s_r & 7));  // swizzled 16B chunk

    for (int kk = 0; kk < 4; kk++) {
        int k0 = kk * 128;
#pragma unroll
        for (int i2 = 0; i2 < 4; i2++) {
            int r = i2 * 32 + s_r;
            int slot = (i2 * 256 + t) * 16;
            load_lds16(A + (size_t)(ibase + r) * DIM + k0 + s_c * 16, As + slot);
            load_lds16(A + (size_t)(jbase + r) * DIM + k0 + s_c * 16, Bs + slot);
        }
        __syncthreads();

        // fragments: lane holds X[m=lm][k = q*32 .. q*32+31] => logical chunks 2q, 2q+1
        intx8 bfv[4];
#pragma unroll
        for (int tn = 0; tn < 4; tn++) {
            int R = wn * 64 + tn * 16 + lm;
            const int4* rowp = (const int4*)(Bs + R * 128);
            int4 lo = rowp[(2 * q) ^ (R & 7)];
            int4 hi = rowp[(2 * q + 1) ^ (R & 7)];
            intx8 v;
            v[0] = lo.x; v[1] = lo.y; v[2] = lo.z; v[3] = lo.w;
            v[4] = hi.x; v[5] = hi.y; v[6] = hi.z; v[7] = hi.w;
            bfv[tn] = v;
        }
#pragma unroll
        for (int tm = 0; tm < 4; tm++) {
            int R = wm * 64 + tm * 16 + lm;
            const int4* rowp = (const int4*)(As + R * 128);
            int4 lo = rowp[(2 * q) ^ (R & 7)];
            int4 hi = rowp[(2 * q + 1) ^ (R & 7)];
            intx8 af;
            af[0] = lo.x; af[1] = lo.y; af[2] = lo.z; af[3] = lo.w;
            af[4] = hi.x; af[5] = hi.y; af[6] = hi.z; af[7] = hi.w;
#pragma unroll
            for (int tn = 0; tn < 4; tn++)
                acc[tm][tn] = __builtin_amdgcn_mfma_scale_f32_16x16x128_f8f6f4(
                    af, bfv[tn], acc[tm][tn], 0, 0,      // cbsz=fp8, blgp=fp8
                    0, 0x7F7F7F7F,                        // scale A = 1.0 (any byte)
                    0, 0x7F7F7F7F);                       // scale B = 1.0
        }
        __syncthreads();
    }

    // C/D layout: col = lane&15, row = (lane>>4)*4 + reg [m89/m91; shape-determined]
    const float INF = __builtin_inff();

    if (!diag) {
        // ---- max-only epilogue (no labels) ----
        float mxJ[4];
#pragma unroll
        for (int tn = 0; tn < 4; tn++) mxJ[tn] = -INF;
#pragma unroll
        for (int tm = 0; tm < 4; tm++) {
#pragma unroll
            for (int r = 0; r < 4; r++) {
                int row_l = wm * 64 + tm * 16 + q * 4 + r;
                float mxI = -INF;
#pragma unroll
                for (int tn = 0; tn < 4; tn++) {
                    float v = acc[tm][tn][r];
                    mxI = fmaxf(mxI, v);
                    mxJ[tn] = fmaxf(mxJ[tn], v);
                }
#pragma unroll
                for (int s = 1; s < 16; s <<= 1)
                    mxI = fmaxf(mxI, __shfl_xor(mxI, s, 64));
                if (lm == 0) redA[row_l][wn] = mxI;
            }
        }
#pragma unroll
        for (int tn = 0; tn < 4; tn++) {
#pragma unroll
            for (int s = 16; s < 64; s <<= 1)
                mxJ[tn] = fmaxf(mxJ[tn], __shfl_xor(mxJ[tn], s, 64));
            if (q == 0) redB[wn * 64 + tn * 16 + lm][wm] = mxJ[tn];
        }
        __syncthreads();
        if (t < 128) {
            atomicMax(&maxEnc[ibase + t], enc_f(fmaxf(redA[t][0], redA[t][1])));
            atomicMax(&maxEnc[jbase + t], enc_f(fmaxf(redB[t][0], redB[t][1])));
        }
    } else {
        // ---- mixed epilogue (min-same / max-diff); extra LDS aliases dead As ----
        int* labi = (int*)As;                             // 512 B
        int* labj = labi + 128;                           // 512 B
        float (*redImn)[2] = (float (*)[2])(labj + 128);  // 1 KB
        float (*redJmn)[2] = redImn + 128;                // 1 KB
        if (t < 128) labi[t] = sortedLabel[ibase + t];
        else labj[t - 128] = sortedLabel[jbase + t - 128];
        __syncthreads();

        int jlab[4];
#pragma unroll
        for (int tn = 0; tn < 4; tn++) jlab[tn] = labj[wn * 64 + tn * 16 + lm];

        float mnJ[4], mxJ[4];
#pragma unroll
        for (int tn = 0; tn < 4; tn++) { mnJ[tn] = INF; mxJ[tn] = -INF; }

#pragma unroll
        for (int tm = 0; tm < 4; tm++) {
#pragma unroll
            for (int r = 0; r < 4; r++) {
                int row_l = wm * 64 + tm * 16 + q * 4 + r;
                int il = labi[row_l];
                float mnI = INF, mxI = -INF;
#pragma unroll
                for (int tn = 0; tn < 4; tn++) {
                    float v = acc[tm][tn][r];
                    bool same = (jlab[tn] == il);
                    float vs = same ? v : INF;
                    float vd = same ? -INF : v;
                    mnI = fminf(mnI, vs);
                    mxI = fmaxf(mxI, vd);
                    mnJ[tn] = fminf(mnJ[tn], vs);
                    mxJ[tn] = fmaxf(mxJ[tn], vd);
                }
#pragma unroll
                for (int s = 1; s < 16; s <<= 1) {
                    mnI = fminf(mnI, __shfl_xor(mnI, s, 64));
                    mxI = fmaxf(mxI, __shfl_xor(mxI, s, 64));
                }
                if (lm == 0) { redImn[row_l][wn] = mnI; redA[row_l][wn] = mxI; }
            }
        }
#pragma unroll
        for (int tn = 0; tn < 4; tn++) {
#pragma unroll
            for (int s = 16; s < 64; s <<= 1) {
                mnJ[tn] = fminf(mnJ[tn], __shfl_xor(mnJ[tn], s, 64));
                mxJ[tn] = fmaxf(mxJ[tn], __shfl_xor(mxJ[tn], s, 64));
            }
            if (q == 0) {
                int col_l = wn * 64 + tn * 16 + lm;
                redJmn[col_l][wm] = mnJ[tn];
                redB[col_l][wm] = mxJ[tn];
            }
        }
        __syncthreads();
        if (t < 128) {
            atomicMin(&minEnc[ibase + t], enc_f(fminf(redImn[t][0], redImn[t][1])));
            atomicMax(&maxEnc[ibase + t], enc_f(fmaxf(redA[t][0], redA[t][1])));
            atomicMin(&minEnc[jbase + t], enc_f(fminf(redJmn[t][0], redJmn[t][1])));
            atomicMax(&maxEnc[jbase + t], enc_f(fmaxf(redB[t][0], redB[t][1])));
        }
    }
}

// 32 blocks; one float atomicAdd per block into pre-zeroed out[0].
__global__ __launch_bounds__(256) void finalize_kernel(const unsigned* __restrict__ minEnc,
                                                       const unsigned* __restrict__ maxEnc,
                                                       const float* __restrict__ cePartial,
                                                       float* __restrict__ out) {
    int gid = blockIdx.x * 256 + threadIdx.x;   // 8192 threads total
    float mn = dec_f(minEnc[gid]);
    float mxv = dec_f(maxEnc[gid]);
    // pos - neg = 2*(max_diff G - min_same G); sq_i cancels, sq_j ≈ 1 (dev ~1e-7)
    float s = fmaxf(2.0f * (mxv - mn) + MARGIN_F, 0.f);
    if (gid < ROWSTAT_BLOCKS) s += cePartial[gid];
#pragma unroll
    for (int sh = 1; sh < 64; sh <<= 1) s += __shfl_xor(s, sh, 64);
    __shared__ float red[4];
    int w = threadIdx.x >> 6, l = threadIdx.x & 63;
    if (l == 0) red[w] = s;
    __syncthreads();
    if (threadIdx.x == 0)
        atomicAdd(out, (red[0] + red[1] + red[2] + red[3]) * (1.0f / (float)N_ROWS));
}

extern "C" void kernel_launch(void* const* d_in, const int* in_sizes, int n_in,
                              void* d_out, int out_size, void* d_ws, size_t ws_size,
                              hipStream_t stream) {
    const float* x = (const float*)d_in[0];
    const int* label = (const int*)d_in[1];
    float* out = (float*)d_out;

    char* ws = (char*)d_ws;
    unsigned char* a8 = (unsigned char*)ws;                      // 4 MB fp8 sorted copy
    char* p = ws + (size_t)N_ROWS * DIM;
    unsigned* minEnc = (unsigned*)p;            p += N_ROWS * 4;
    unsigned* maxEnc = (unsigned*)p;            p += N_ROWS * 4;
    float* cePartial = (float*)p;               p += ROWSTAT_BLOCKS * 4;
    int* offsetArr = (int*)p;                   p += NLAB * 4;
    int* cnt = (int*)p;                         p += NLAB * 4;
    int* sortedLabel = (int*)p;                 p += N_ROWS * 4;

    histscan_kernel<<<1, 512, 0, stream>>>(label, offsetArr, cnt, out);
    rowstats_kernel<<<ROWSTAT_BLOCKS, 256, 0, stream>>>(x, label, offsetArr, cnt, a8,
                                                        sortedLabel, cePartial, minEnc, maxEnc);
    gemm_kernel<<<NTILE, 256, 0, stream>>>(a8, sortedLabel, minEnc, maxEnc);
    finalize_kernel<<<32, 256, 0, stream>>>(minEnc, maxEnc, cePartial, out);
}

// Round 12
// 103.515 us; speedup vs baseline: 5.7006x; 1.0867x over previous
//
#include <hip/hip_runtime.h>
#include <hip/hip_bf16.h>
#include <stdint.h>

#define N_ROWS 8192
#define DIM 512
#define NLAB 512
#define MARGIN_F 0.35f
#define NBLK 64                        // 8192/128 row-blocks
#define NPURE 1953                     // tiles with bi-bj >= 2
#define NDIAG 127                      // diagonal (64) + subdiagonal (63)
#define NTILE (NPURE + NDIAG)          // 2080
#define ROWSTAT_BLOCKS (N_ROWS / 4)    // 2048

typedef __attribute__((ext_vector_type(4))) float floatx4;
typedef __attribute__((ext_vector_type(8))) int intx8;

// order-preserving float->uint map (for atomicMin/Max on floats)
__device__ __forceinline__ unsigned enc_f(float f) {
    unsigned u = __float_as_uint(f);
    return (u & 0x80000000u) ? ~u : (u | 0x80000000u);
}
__device__ __forceinline__ float dec_f(unsigned e) {
    unsigned u = (e & 0x80000000u) ? (e ^ 0x80000000u) : ~e;
    return __uint_as_float(u);
}

__device__ __forceinline__ void load_lds16(const void* g, void* l) {
    __builtin_amdgcn_global_load_lds((__attribute__((address_space(1))) void*)(void*)g,
                                     (__attribute__((address_space(3))) void*)l, 16, 0, 0);
}

// R12: 16-lane reduce on the VALU pipe via DPP row-rotate (row = 16 lanes).
// Replaces __shfl_xor chains (ds_swizzle = DS pipe, contended by the K-loop's
// ds_read_b128 stream of co-resident blocks). GCNDPPCombine fuses mov+max.
__device__ __forceinline__ float rowmax16(float x) {
    int v, y;
    v = __float_as_int(x);
    y = __builtin_amdgcn_update_dpp(v, v, 0x121, 0xf, 0xf, true);  // row_ror:1
    x = fmaxf(x, __int_as_float(y)); v = __float_as_int(x);
    y = __builtin_amdgcn_update_dpp(v, v, 0x122, 0xf, 0xf, true);  // row_ror:2
    x = fmaxf(x, __int_as_float(y)); v = __float_as_int(x);
    y = __builtin_amdgcn_update_dpp(v, v, 0x124, 0xf, 0xf, true);  // row_ror:4
    x = fmaxf(x, __int_as_float(y)); v = __float_as_int(x);
    y = __builtin_amdgcn_update_dpp(v, v, 0x128, 0xf, 0xf, true);  // row_ror:8
    return fmaxf(x, __int_as_float(y));
}
__device__ __forceinline__ float rowmin16(float x) {
    int v, y;
    v = __float_as_int(x);
    y = __builtin_amdgcn_update_dpp(v, v, 0x121, 0xf, 0xf, true);
    x = fminf(x, __int_as_float(y)); v = __float_as_int(x);
    y = __builtin_amdgcn_update_dpp(v, v, 0x122, 0xf, 0xf, true);
    x = fminf(x, __int_as_float(y)); v = __float_as_int(x);
    y = __builtin_amdgcn_update_dpp(v, v, 0x124, 0xf, 0xf, true);
    x = fminf(x, __int_as_float(y)); v = __float_as_int(x);
    y = __builtin_amdgcn_update_dpp(v, v, 0x128, 0xf, 0xf, true);
    return fminf(x, __int_as_float(y));
}

// Single block: histogram of labels + exclusive scan -> offsets, zero rank counters + out.
__global__ __launch_bounds__(512) void histscan_kernel(const int* __restrict__ label,
                                                       int* __restrict__ offsetArr,
                                                       int* __restrict__ cnt,
                                                       float* __restrict__ out) {
    __shared__ int h[NLAB];
    __shared__ int sc[NLAB];
    int t = threadIdx.x;
    h[t] = 0;
    __syncthreads();
    for (int i = t; i < N_ROWS; i += 512) atomicAdd(&h[label[i]], 1);
    __syncthreads();
    int v = h[t];
    sc[t] = v;
    __syncthreads();
    for (int d = 1; d < NLAB; d <<= 1) {
        int add = (t >= d) ? sc[t - d] : 0;
        __syncthreads();
        sc[t] += add;
        __syncthreads();
    }
    offsetArr[t] = sc[t] - v;   // exclusive prefix
    cnt[t] = 0;
    if (t == 0) out[0] = 0.f;
}

// One wave per row: CE partial + fp8(e4m3) conversion scattered to label-sorted position.
// Also initializes minEnc/maxEnc.
__global__ __launch_bounds__(256) void rowstats_kernel(const float* __restrict__ x,
                                                       const int* __restrict__ label,
                                                       const int* __restrict__ offsetArr,
                                                       int* __restrict__ cnt,
                                                       unsigned char* __restrict__ a8,
                                                       int* __restrict__ sortedLabel,
                                                       float* __restrict__ cePartial,
                                                       unsigned* __restrict__ minEnc,
                                                       unsigned* __restrict__ maxEnc) {
    int gid = blockIdx.x * 256 + threadIdx.x;
    if (gid < N_ROWS) { minEnc[gid] = 0xFFFFFFFFu; maxEnc[gid] = 0u; }

    int w = threadIdx.x >> 6;
    int row = blockIdx.x * 4 + w;
    int l = threadIdx.x & 63;
    const float* xr = x + (size_t)row * DIM;
    float4 v0 = ((const float4*)xr)[2 * l];
    float4 v1 = ((const float4*)xr)[2 * l + 1];
    float vals[8] = {v0.x, v0.y, v0.z, v0.w, v1.x, v1.y, v1.z, v1.w};

    float mx = vals[0];
#pragma unroll
    for (int i = 1; i < 8; i++) mx = fmaxf(mx, vals[i]);
#pragma unroll
    for (int s = 1; s < 64; s <<= 1) mx = fmaxf(mx, __shfl_xor(mx, s, 64));

    float se = 0.f;
#pragma unroll
    for (int i = 0; i < 8; i++) se += expf(vals[i] - mx);
#pragma unroll
    for (int s = 1; s < 64; s <<= 1) se += __shfl_xor(se, s, 64);

    // sorted position for this row (counting-sort rank)
    int pos = 0;
    if (l == 0) {
        int lab = label[row];
        pos = offsetArr[lab] + atomicAdd(&cnt[lab], 1);
        sortedLabel[pos] = lab;
    }
    pos = __shfl(pos, 0, 64);

    // pack 8 fp8 e4m3 and store 8B to the sorted slot
    int w0 = __builtin_amdgcn_cvt_pk_fp8_f32(vals[0], vals[1], 0, false);
    w0 = __builtin_amdgcn_cvt_pk_fp8_f32(vals[2], vals[3], w0, true);
    int w1 = __builtin_amdgcn_cvt_pk_fp8_f32(vals[4], vals[5], 0, false);
    w1 = __builtin_amdgcn_cvt_pk_fp8_f32(vals[6], vals[7], w1, true);
    ((uint2*)(a8 + (size_t)pos * DIM))[l] = make_uint2((unsigned)w0, (unsigned)w1);

    __shared__ float wsum[4];
    if (l == 0) {
        float tl = xr[label[row]];
        wsum[w] = mx + logf(se) - tl;
    }
    __syncthreads();
    if (threadIdx.x == 0)
        cePartial[blockIdx.x] = wsum[0] + wsum[1] + wsum[2] + wsum[3];
}

// Merged GEMM on fp8: blocks [0, NDIAG) diag/subdiag tiles (mixed epilogue),
// blocks [NDIAG, NTILE) pure tiles (max-only). 128x128 tile, BK=128,
// 16B-granule XOR-swizzled LDS, mfma_scale 16x16x128 f8f6f4 (scale=1.0),
// 2x2 waves x 4x4 frags. launch_bounds(256,3) -- the session-proven config.
//
// R12 (single concept vs the 110.3 baseline): epilogue off the DS pipe.
// R10 ablation measured epilogue ~12us; it was ~70 __shfl_xor/thread --
// ds_swizzle ops on the SAME DS pipe as the K-loop's ds_read_b128 stream
// (and co-resident blocks' K-loops -- a plausible anti-overlap mechanism).
//   (a) 16-lane I-side reduces -> DPP row_ror rotate-reduce (VALU pipe;
//       VALUBusy measured ~14%, headroom).
//   (b) cross-row J-side reduces (xor16/xor32) -> eliminated: each q-group
//       stores its partial to redB[col][wm*4+q]; final 128-thread combine
//       reads 8 slots (7 extra fmax, VALU).
// Epilogue cross-lane DS ops: ~72/thread -> 0.
__global__ __launch_bounds__(256, 3) void gemm_kernel(const unsigned char* __restrict__ A,
                                                      const int* __restrict__ sortedLabel,
                                                      unsigned* __restrict__ minEnc,
                                                      unsigned* __restrict__ maxEnc) {
    __shared__ unsigned char As[128 * 128];   // 16 KB
    __shared__ unsigned char Bs[128 * 128];   // 16 KB
    __shared__ float redA[128][2];            // I-side max (lm==0 writers)
    __shared__ float redB[128][8];            // J-side max partials [wm*4+q]

    int b = blockIdx.x;
    bool diag = (b < NDIAG);
    int bi, bj;
    if (diag) {
        bi = (b < 64) ? b : (b - 63);
        bj = (b < 64) ? b : (b - 64);
    } else {
        int p = b - NDIAG;
        int ci = (int)((sqrtf(8.0f * (float)p + 1.0f) - 1.0f) * 0.5f);
        while ((ci + 1) * (ci + 2) / 2 <= p) ci++;
        while (ci * (ci + 1) / 2 > p) ci--;
        bj = p - ci * (ci + 1) / 2;
        bi = ci + 2;
    }
    int ibase = bi * 128, jbase = bj * 128;

    int t = threadIdx.x;
    int w = t >> 6, l = t & 63;
    int wm = w >> 1, wn = w & 1;
    int q = l >> 4, lm = l & 15;

    floatx4 acc[4][4];
#pragma unroll
    for (int a = 0; a < 4; a++)
#pragma unroll
        for (int c = 0; c < 4; c++) acc[a][c] = (floatx4)0.f;

    // per-lane staging geometry (loop-invariant)
    int s_r = t >> 3;                 // row within tile for this thread's slot
    int s_c = ((t & 7) ^ (s_r & 7));  // swizzled 16B chunk

    for (int kk = 0; kk < 4; kk++) {
        int k0 = kk * 128;
#pragma unroll
        for (int i2 = 0; i2 < 4; i2++) {
            int r = i2 * 32 + s_r;
            int slot = (i2 * 256 + t) * 16;
            load_lds16(A + (size_t)(ibase + r) * DIM + k0 + s_c * 16, As + slot);
            load_lds16(A + (size_t)(jbase + r) * DIM + k0 + s_c * 16, Bs + slot);
        }
        __syncthreads();

        // fragments: lane holds X[m=lm][k = q*32 .. q*32+31] => logical chunks 2q, 2q+1
        intx8 bfv[4];
#pragma unroll
        for (int tn = 0; tn < 4; tn++) {
            int R = wn * 64 + tn * 16 + lm;
            const int4* rowp = (const int4*)(Bs + R * 128);
            int4 lo = rowp[(2 * q) ^ (R & 7)];
            int4 hi = rowp[(2 * q + 1) ^ (R & 7)];
            intx8 v;
            v[0] = lo.x; v[1] = lo.y; v[2] = lo.z; v[3] = lo.w;
            v[4] = hi.x; v[5] = hi.y; v[6] = hi.z; v[7] = hi.w;
            bfv[tn] = v;
        }
#pragma unroll
        for (int tm = 0; tm < 4; tm++) {
            int R = wm * 64 + tm * 16 + lm;
            const int4* rowp = (const int4*)(As + R * 128);
            int4 lo = rowp[(2 * q) ^ (R & 7)];
            int4 hi = rowp[(2 * q + 1) ^ (R & 7)];
            intx8 af;
            af[0] = lo.x; af[1] = lo.y; af[2] = lo.z; af[3] = lo.w;
            af[4] = hi.x; af[5] = hi.y; af[6] = hi.z; af[7] = hi.w;
#pragma unroll
            for (int tn = 0; tn < 4; tn++)
                acc[tm][tn] = __builtin_amdgcn_mfma_scale_f32_16x16x128_f8f6f4(
                    af, bfv[tn], acc[tm][tn], 0, 0,      // cbsz=fp8, blgp=fp8
                    0, 0x7F7F7F7F,                        // scale A = 1.0 (any byte)
                    0, 0x7F7F7F7F);                       // scale B = 1.0
        }
        __syncthreads();
    }

    // C/D layout: col = lane&15, row = (lane>>4)*4 + reg [m89/m91; shape-determined]
    const float INF = __builtin_inff();

    if (!diag) {
        // ---- max-only epilogue (no labels), DS-free reductions ----
        float mxJ[4];
#pragma unroll
        for (int tn = 0; tn < 4; tn++) mxJ[tn] = -INF;
#pragma unroll
        for (int tm = 0; tm < 4; tm++) {
#pragma unroll
            for (int r = 0; r < 4; r++) {
                int row_l = wm * 64 + tm * 16 + q * 4 + r;
                float mxI = -INF;
#pragma unroll
                for (int tn = 0; tn < 4; tn++) {
                    float v = acc[tm][tn][r];
                    mxI = fmaxf(mxI, v);
                    mxJ[tn] = fmaxf(mxJ[tn], v);
                }
                mxI = rowmax16(mxI);                 // DPP, VALU pipe
                if (lm == 0) redA[row_l][wn] = mxI;
            }
        }
#pragma unroll
        for (int tn = 0; tn < 4; tn++)               // no cross-row shuffles:
            redB[wn * 64 + tn * 16 + lm][wm * 4 + q] = mxJ[tn];
        __syncthreads();
        if (t < 128) {
            atomicMax(&maxEnc[ibase + t], enc_f(fmaxf(redA[t][0], redA[t][1])));
            float vj = redB[t][0];
#pragma unroll
            for (int s = 1; s < 8; s++) vj = fmaxf(vj, redB[t][s]);
            atomicMax(&maxEnc[jbase + t], enc_f(vj));
        }
    } else {
        // ---- mixed epilogue (min-same / max-diff); extra LDS aliases dead As ----
        int* labi = (int*)As;                             // 512 B
        int* labj = labi + 128;                           // 512 B
        float (*redImn)[2] = (float (*)[2])(labj + 128);  // 1 KB
        float (*redJmn)[8] = (float (*)[8])(redImn + 128);// 4 KB
        if (t < 128) labi[t] = sortedLabel[ibase + t];
        else labj[t - 128] = sortedLabel[jbase + t - 128];
        __syncthreads();

        int jlab[4];
#pragma unroll
        for (int tn = 0; tn < 4; tn++) jlab[tn] = labj[wn * 64 + tn * 16 + lm];

        float mnJ[4], mxJ[4];
#pragma unroll
        for (int tn = 0; tn < 4; tn++) { mnJ[tn] = INF; mxJ[tn] = -INF; }

#pragma unroll
        for (int tm = 0; tm < 4; tm++) {
#pragma unroll
            for (int r = 0; r < 4; r++) {
                int row_l = wm * 64 + tm * 16 + q * 4 + r;
                int il = labi[row_l];
                float mnI = INF, mxI = -INF;
#pragma unroll
                for (int tn = 0; tn < 4; tn++) {
                    float v = acc[tm][tn][r];
                    bool same = (jlab[tn] == il);
                    float vs = same ? v : INF;
                    float vd = same ? -INF : v;
                    mnI = fminf(mnI, vs);
                    mxI = fmaxf(mxI, vd);
                    mnJ[tn] = fminf(mnJ[tn], vs);
                    mxJ[tn] = fmaxf(mxJ[tn], vd);
                }
                mnI = rowmin16(mnI);                 // DPP, VALU pipe
                mxI = rowmax16(mxI);
                if (lm == 0) { redImn[row_l][wn] = mnI; redA[row_l][wn] = mxI; }
            }
        }
#pragma unroll
        for (int tn = 0; tn < 4; tn++) {             // no cross-row shuffles
            int col_l = wn * 64 + tn * 16 + lm;
            redJmn[col_l][wm * 4 + q] = mnJ[tn];
            redB[col_l][wm * 4 + q] = mxJ[tn];
        }
        __syncthreads();
        if (t < 128) {
            atomicMin(&minEnc[ibase + t], enc_f(fminf(redImn[t][0], redImn[t][1])));
            atomicMax(&maxEnc[ibase + t], enc_f(fmaxf(redA[t][0], redA[t][1])));
            float vjm = redJmn[t][0], vjx = redB[t][0];
#pragma unroll
            for (int s = 1; s < 8; s++) {
                vjm = fminf(vjm, redJmn[t][s]);
                vjx = fmaxf(vjx, redB[t][s]);
            }
            atomicMin(&minEnc[jbase + t], enc_f(vjm));
            atomicMax(&maxEnc[jbase + t], enc_f(vjx));
        }
    }
}

// 32 blocks; one float atomicAdd per block into pre-zeroed out[0].
__global__ __launch_bounds__(256) void finalize_kernel(const unsigned* __restrict__ minEnc,
                                                       const unsigned* __restrict__ maxEnc,
                                                       const float* __restrict__ cePartial,
                                                       float* __restrict__ out) {
    int gid = blockIdx.x * 256 + threadIdx.x;   // 8192 threads total
    float mn = dec_f(minEnc[gid]);
    float mxv = dec_f(maxEnc[gid]);
    // pos - neg = 2*(max_diff G - min_same G); sq_i cancels, sq_j ≈ 1 (dev ~1e-7)
    float s = fmaxf(2.0f * (mxv - mn) + MARGIN_F, 0.f);
    if (gid < ROWSTAT_BLOCKS) s += cePartial[gid];
#pragma unroll
    for (int sh = 1; sh < 64; sh <<= 1) s += __shfl_xor(s, sh, 64);
    __shared__ float red[4];
    int w = threadIdx.x >> 6, l = threadIdx.x & 63;
    if (l == 0) red[w] = s;
    __syncthreads();
    if (threadIdx.x == 0)
        atomicAdd(out, (red[0] + red[1] + red[2] + red[3]) * (1.0f / (float)N_ROWS));
}

extern "C" void kernel_launch(void* const* d_in, const int* in_sizes, int n_in,
                              void* d_out, int out_size, void* d_ws, size_t ws_size,
                              hipStream_t stream) {
    const float* x = (const float*)d_in[0];
    const int* label = (const int*)d_in[1];
    float* out = (float*)d_out;

    char* ws = (char*)d_ws;
    unsigned char* a8 = (unsigned char*)ws;                      // 4 MB fp8 sorted copy
    char* p = ws + (size_t)N_ROWS * DIM;
    unsigned* minEnc = (unsigned*)p;            p += N_ROWS * 4;
    unsigned* maxEnc = (unsigned*)p;            p += N_ROWS * 4;
    float* cePartial = (float*)p;               p += ROWSTAT_BLOCKS * 4;
    int* offsetArr = (int*)p;                   p += NLAB * 4;
    int* cnt = (int*)p;                         p += NLAB * 4;
    int* sortedLabel = (int*)p;                 p += N_ROWS * 4;

    histscan_kernel<<<1, 512, 0, stream>>>(label, offsetArr, cnt, out);
    rowstats_kernel<<<ROWSTAT_BLOCKS, 256, 0, stream>>>(x, label, offsetArr, cnt, a8,
                                                        sortedLabel, cePartial, minEnc, maxEnc);
    gemm_kernel<<<NTILE, 256, 0, stream>>>(a8, sortedLabel, minEnc, maxEnc);
    finalize_kernel<<<32, 256, 0, stream>>>(minEnc, maxEnc, cePartial, out);
}